// Round 2
// 350.437 us; speedup vs baseline: 1.0055x; 1.0055x over previous
//
#include <hip/hip_runtime.h>

// Problem constants
#define NB    2048     // users / segments
#define NP    16384    // posts
#define LL    50       // tokens per post
#define DD    300      // embedding dim
#define DP    320      // d padded to multiple of 32 (MFMA K tiles)
#define TP    52       // t rows incl. zero pad (48 outputs + 4 shift overhang)
#define NTOT  300      // total filters (100 per conv)
#define NPADF 320      // filters padded to 20 N-tiles of 16
#define INFEAT 768
#define HID2  128
#define UPB   4        // users per conv block
#define FCM   16       // users per fc block

typedef short v8s __attribute__((ext_vector_type(8)));
typedef float v4f __attribute__((ext_vector_type(4)));

__device__ __forceinline__ unsigned short f2bf(float f) {
    union { float f; unsigned u; } v; v.f = f;
    return (unsigned short)((v.u + 0x7FFF + ((v.u >> 16) & 1)) >> 16);  // RNE
}
__device__ __forceinline__ float bf2f(unsigned short u) {
    union { unsigned u; float f; } v; v.u = ((unsigned)u) << 16; return v.f;
}
__device__ __forceinline__ int lower_bound_i(const int* __restrict__ a, int n, int v) {
    int lo = 0, hi = n;
    while (lo < hi) { int mid = (lo + hi) >> 1; if (a[mid] < v) lo = mid + 1; else hi = mid; }
    return lo;
}

// ---- generic fp32 -> bf16 (used for emb table and fc_w1) ----
__global__ void emb_cvt(const float* __restrict__ in, unsigned short* __restrict__ out, int n4) {
    int i = blockIdx.x * blockDim.x + threadIdx.x;
    if (i >= n4) return;
    float4 v = ((const float4*)in)[i];
    ushort4 o; o.x = f2bf(v.x); o.y = f2bf(v.y); o.z = f2bf(v.z); o.w = f2bf(v.w);
    ((ushort4*)out)[i] = o;
}

// ---- conv weights -> bf16 fragment-order W5f[step=kt*5+s][nt][lane][8] + bias_all ----
__global__ void prep_w(const float* __restrict__ w3, const float* __restrict__ w4,
                       const float* __restrict__ w5,
                       const float* __restrict__ b3, const float* __restrict__ b4,
                       const float* __restrict__ b5,
                       unsigned short* __restrict__ W5f, float* __restrict__ bias_all) {
    int idx = blockIdx.x * blockDim.x + threadIdx.x;
    if (idx < NPADF) {
        float bv = 0.f;
        if (idx < 100) bv = b3[idx];
        else if (idx < 200) bv = b4[idx - 100];
        else if (idx < 300) bv = b5[idx - 200];
        bias_all[idx] = bv;
    }
    if (idx >= 10 * 5 * 20 * 512) return;
    int j    = idx & 7;
    int lane = (idx >> 3) & 63;
    int rest = idx >> 9;            // kt*100 + s*20 + nt
    int nt = rest % 20;
    int s  = (rest / 20) % 5;
    int kt = rest / 100;
    int col = lane & 15, quad = lane >> 4;
    int nf = nt * 16 + col;
    int d  = kt * 32 + quad * 8 + j;
    float v = 0.f;
    if (nf < NTOT && d < DD) {
        int cls = nf / 100, f = nf % 100, K = cls + 3;
        if (s < K) {
            const float* w = (cls == 0) ? w3 : (cls == 1) ? w4 : w5;
            v = w[(f * DD + d) * K + s];
        }
    }
    W5f[idx] = f2bf(v);
}

// ---- ragged segment-mean -> bf16 hist[b][52][320], vectorized ushort4 gather ----
#define PCHUNK 32
__global__ __launch_bounds__(512, 1) void gather_kernel(
    const int* __restrict__ hist_tokens, const int* __restrict__ seg,
    const unsigned short* __restrict__ embb, unsigned short* __restrict__ histb)
{
    __shared__ int tokoff[PCHUNK * LL];
    const int b = blockIdx.x, tid = threadIdx.x;
    const int lo = lower_bound_i(seg, NP, b);
    const int hi = lower_bound_i(seg, NP, b + 1);
    const float inv = 1.0f / fmaxf((float)(hi - lo), 1.0f);

    int toff[8], doff[8];
    #pragma unroll
    for (int j = 0; j < 8; ++j) {
        int idx = tid + 512 * j;
        if (idx < 3750) { toff[j] = idx / 75; doff[j] = (idx % 75) * 4; }
        else            { toff[j] = 0;        doff[j] = 0; }
    }
    const bool has8 = (tid < 166);

    float4 acc[8];
    #pragma unroll
    for (int j = 0; j < 8; ++j) acc[j] = make_float4(0.f, 0.f, 0.f, 0.f);

    for (int p0 = lo; p0 < hi; p0 += PCHUNK) {
        const int pc = min(PCHUNK, hi - p0);
        __syncthreads();
        for (int j = tid; j < pc * LL; j += 512)
            tokoff[j] = hist_tokens[p0 * LL + j] * DD;
        __syncthreads();
        for (int pp = 0; pp < pc; ++pp) {
            const int* tr = tokoff + pp * LL;
            #pragma unroll
            for (int j = 0; j < 7; ++j) {
                const ushort4 v = *(const ushort4*)(embb + tr[toff[j]] + doff[j]);
                acc[j].x += bf2f(v.x); acc[j].y += bf2f(v.y);
                acc[j].z += bf2f(v.z); acc[j].w += bf2f(v.w);
            }
            if (has8) {
                const ushort4 v = *(const ushort4*)(embb + tr[toff[7]] + doff[7]);
                acc[7].x += bf2f(v.x); acc[7].y += bf2f(v.y);
                acc[7].z += bf2f(v.z); acc[7].w += bf2f(v.w);
            }
        }
    }

    unsigned short* hb = histb + (size_t)b * TP * DP;
    #pragma unroll
    for (int j = 0; j < 8; ++j) {
        if (j < 7 || has8) {
            ushort4 o;
            o.x = f2bf(acc[j].x * inv); o.y = f2bf(acc[j].y * inv);
            o.z = f2bf(acc[j].z * inv); o.w = f2bf(acc[j].w * inv);
            *(ushort4*)(hb + toff[j] * DP + doff[j]) = o;
        }
    }
    for (int i = tid; i < 640 + 1000; i += 512) {
        int t, d;
        if (i < 640) { t = 50 + i / 320; d = i % 320; }
        else         { int j = i - 640; t = j / 20; d = 300 + j % 20; }
        hb[t * DP + d] = 0;
    }
}

// ---- conv: 4 users/block, 12 waves = 4 users x 3 n-groups {0-6,7-13,14-18}.
//      Each wave: all 3 m-tiles x its n-group -> acc[3][7] (84 AGPR), 3 waves/SIMD.
//      wave = g*4+u so each SIMD hosts one wave per n-group -> tap-skip balanced.
//      Compile-time tap-skip: s=3 only tiles>=6, s=4 only tiles>=12 (zero weights
//      there by construction; verified vs reference).
//      Schedule: single LDS buffers, TWO barriers/step:
//        bar1 -> ds_write staged regs -> bar2 -> issue next loads -> ds_read+MFMA.
//      Writes live strictly in [bar1,bar2], reads in [bar2,next bar1]: race-free. ----
__global__ __launch_bounds__(768, 3) void conv_kernel(
    const unsigned short* __restrict__ histb, const unsigned short* __restrict__ W5f,
    const float* __restrict__ bias_all,
    const float* __restrict__ hist_w, const float* __restrict__ hist_b,
    float* __restrict__ out)
{
    __shared__ __align__(16) unsigned short sA[UPB * 52 * 40];   // 16,640 B
    __shared__ __align__(16) unsigned short sB[19 * 512];        // 19,456 B
    __shared__ __align__(16) float fpool[UPB * NPADF];           //  5,120 B

    const int b = blockIdx.x, tid = threadIdx.x;
    const int wave = tid >> 6, lane = tid & 63;
    const int col = lane & 15, quad = lane >> 4;
    const int u = wave & 3, g = wave >> 2;      // user 0..3, n-group 0..2
    const int base = (g == 2) ? 14 : g * 7;     // first tile of group
    const int cnt  = (g == 2) ? 5  : 7;         // live tiles in group

    const unsigned short* hbase = histb + (size_t)(b * UPB) * TP * DP;

    // A staging chunk decode (832 chunks: 4 users x 52 rows x 4 ch of 8 ushorts)
    const int c0 = tid;
    const int a0_uu = c0 / 208, a0_r = c0 % 208;
    const int a0_row = a0_r >> 2, a0_ch = a0_r & 3;
    const int c1 = tid + 768;
    const int a1_uu = c1 / 208, a1_r = c1 % 208;
    const int a1_row = a1_r >> 2, a1_ch = a1_r & 3;
    const bool hasA1 = (tid < 64);              // 832 - 768

    v4f acc[3][7];
    #pragma unroll
    for (int m = 0; m < 3; ++m)
        #pragma unroll
        for (int j = 0; j < 7; ++j)
            acc[m][j] = (v4f){0.f, 0.f, 0.f, 0.f};

    // ---- prologue: load A(kt=0) and B(step=0) into registers (no LDS writes) ----
    v8s t0 = {}, t1 = {}, a0v = {}, a1v = {};
    a0v = *(const v8s*)(hbase + (size_t)a0_uu * TP * DP + a0_row * DP + a0_ch * 8);
    if (hasA1)
        a1v = *(const v8s*)(hbase + (size_t)a1_uu * TP * DP + a1_row * DP + a1_ch * 8);
    t0 = *(const v8s*)(W5f + (size_t)tid * 8);
    if (tid < 448) t1 = *(const v8s*)(W5f + (size_t)(tid + 768) * 8);

    for (int kt = 0; kt < 10; ++kt) {
        #pragma unroll
        for (int s = 0; s < 5; ++s) {
            const int step = kt * 5 + s;
            const int lo   = (s == 3) ? 6 : (s == 4) ? 12 : 0;   // live tile range [lo,19)
            const int Cc   = (19 - lo) * 64;                     // staged chunks this step

            __syncthreads();               // bar1: all reads of previous step done
            if (s == 0) {
                *(v8s*)(sA + (a0_uu * 52 + a0_row) * 40 + a0_ch * 8) = a0v;
                if (hasA1) *(v8s*)(sA + (a1_uu * 52 + a1_row) * 40 + a1_ch * 8) = a1v;
            }
            {
                unsigned short* db = sB + lo * 512;
                if (tid < Cc)       *(v8s*)(db + tid * 8) = t0;
                if (tid + 768 < Cc) *(v8s*)(db + (tid + 768) * 8) = t1;
            }
            __syncthreads();               // bar2: staging visible

            // -- issue next step's global loads (consumed at next bar1) --
            if ((s < 4) || (kt < 9)) {
                const int sn  = (s == 4) ? 0 : s + 1;
                const int lon = (sn == 3) ? 6 : (sn == 4) ? 12 : 0;
                const int Cn  = (19 - lon) * 64;
                const unsigned short* gb = W5f + (size_t)(step + 1) * 10240 + lon * 512;
                if (tid < Cn)       t0 = *(const v8s*)(gb + tid * 8);
                if (tid + 768 < Cn) t1 = *(const v8s*)(gb + (tid + 768) * 8);
            }
            if (s == 4 && kt < 9) {
                const int ko = (kt + 1) * 32;
                a0v = *(const v8s*)(hbase + (size_t)a0_uu * TP * DP + a0_row * DP + ko + a0_ch * 8);
                if (hasA1)
                    a1v = *(const v8s*)(hbase + (size_t)a1_uu * TP * DP + a1_row * DP + ko + a1_ch * 8);
            }

            // -- compute: 3 A frags + up to 7 B frags, 3 MFMA per B frag --
            const unsigned short* Arow = sA + (u * 52 + col + s) * 40 + quad * 8;
            const v8s am0 = *(const v8s*)(Arow);
            const v8s am1 = *(const v8s*)(Arow + 640);    // +16 rows * 40
            const v8s am2 = *(const v8s*)(Arow + 1280);   // +32 rows * 40
            #pragma unroll
            for (int j = 0; j < 7; ++j) {
                const int t = base + j;
                if (j < cnt && t >= lo) {
                    const v8s bf = *(const v8s*)(sB + t * 512 + lane * 8);
                    acc[0][j] = __builtin_amdgcn_mfma_f32_16x16x32_bf16(am0, bf, acc[0][j], 0, 0, 0);
                    acc[1][j] = __builtin_amdgcn_mfma_f32_16x16x32_bf16(am1, bf, acc[1][j], 0, 0, 0);
                    acc[2][j] = __builtin_amdgcn_mfma_f32_16x16x32_bf16(am2, bf, acc[2][j], 0, 0, 0);
                }
            }
        }
    }

    // maxpool + bias + relu -> fpool (wave-local: each wave owns all m for its tiles)
    #pragma unroll
    for (int j = 0; j < 7; ++j) {
        if (j < cnt) {
            const int nf = (base + j) * 16 + col;
            const int Tout = 48 - nf / 100;        // 48/47/46 per class
            float mx = -1e30f;
            #pragma unroll
            for (int m = 0; m < 3; ++m)
                #pragma unroll
                for (int r = 0; r < 4; ++r) {
                    const int t = m * 16 + quad * 4 + r;
                    if (t < Tout) mx = fmaxf(mx, acc[m][j][r]);
                }
            mx = fmaxf(mx, __shfl_xor(mx, 16, 64));
            mx = fmaxf(mx, __shfl_xor(mx, 32, 64));
            if (quad == 0 && nf < NTOT)
                fpool[u * NPADF + nf] = fmaxf(0.f, mx + bias_all[nf]);
        }
    }
    __syncthreads();

    // rec = fpool @ hist_w.T + hist_b
    if (tid < UPB * 64) {
        const int uu = tid >> 6, o = tid & 63;
        const float4* fw = (const float4*)(hist_w + o * NTOT);
        const float4* fp = (const float4*)(fpool + uu * NPADF);
        float sum = 0.f;
        #pragma unroll
        for (int q = 0; q < NTOT / 4; ++q) {
            float4 aa = fp[q], ww = fw[q];
            sum += aa.x * ww.x + aa.y * ww.y + aa.z * ww.z + aa.w * ww.w;
        }
        out[(b * UPB + uu) * 64 + o] = sum + hist_b[o];
    }
}

// ---- fc via MFMA: h = relu(x[root] @ w1b.T + b1) ; out += h @ w2.T + b2 ----
__global__ __launch_bounds__(256, 1) void fc_mfma(
    const float* __restrict__ x, const int* __restrict__ rootindex,
    const unsigned short* __restrict__ w1b, const float* __restrict__ b1,
    const float* __restrict__ w2, const float* __restrict__ b2,
    float* __restrict__ out)
{
    __shared__ __align__(16) unsigned short sA[FCM * 72];   // 16 rows x 64k (pad 72)
    __shared__ __align__(16) float hl[FCM * 132];           // h tile, stride 132
    __shared__ __align__(16) float w2l[64 * 129];           // w2 staged, stride 129
    __shared__ int roots[FCM];

    const int b = blockIdx.x, tid = threadIdx.x;
    if (tid < FCM) roots[tid] = rootindex[b * FCM + tid];
    for (int i = tid; i < 64 * HID2; i += 256)
        w2l[(i >> 7) * 129 + (i & 127)] = w2[i];
    __syncthreads();

    const int wave = tid >> 6, lane = tid & 63;
    const int col = lane & 15, quad = lane >> 4;

    v4f acc[2];
    acc[0] = (v4f){0.f, 0.f, 0.f, 0.f};
    acc[1] = (v4f){0.f, 0.f, 0.f, 0.f};

    const int r_st = tid >> 4, q_st = tid & 15;

    for (int kt = 0; kt < 12; ++kt) {
        __syncthreads();
        float4 v = *(const float4*)(x + (size_t)roots[r_st] * INFEAT + kt * 64 + q_st * 4);
        ushort4 o; o.x = f2bf(v.x); o.y = f2bf(v.y); o.z = f2bf(v.z); o.w = f2bf(v.w);
        *(ushort4*)(sA + r_st * 72 + q_st * 4) = o;
        __syncthreads();
        #pragma unroll
        for (int kc = 0; kc < 2; ++kc) {
            const v8s a = *(const v8s*)(sA + col * 72 + kc * 32 + quad * 8);
            #pragma unroll
            for (int n = 0; n < 2; ++n) {
                const int nf = (wave * 2 + n) * 16 + col;
                const v8s bfr = *(const v8s*)(w1b + (size_t)nf * INFEAT + kt * 64 + kc * 32 + quad * 8);
                acc[n] = __builtin_amdgcn_mfma_f32_16x16x32_bf16(a, bfr, acc[n], 0, 0, 0);
            }
        }
    }

    #pragma unroll
    for (int nt = 0; nt < 2; ++nt) {
        const int n = (wave * 2 + nt) * 16 + col;
        const float bv = b1[n];
        #pragma unroll
        for (int r = 0; r < 4; ++r)
            hl[(quad * 4 + r) * 132 + n] = fmaxf(acc[nt][r] + bv, 0.f);
    }
    __syncthreads();

    {
        const int o = tid & 63, ug = tid >> 6;
        const float b2v = b2[o];
        const float* wrow = w2l + o * 129;
        #pragma unroll
        for (int i = 0; i < 4; ++i) {
            const int u = ug * 4 + i;
            const float* hrow = hl + u * 132;
            float s = 0.f;
            #pragma unroll 16
            for (int k = 0; k < HID2; ++k) s += hrow[k] * wrow[k];
            out[(b * FCM + u) * 64 + o] += s + b2v;
        }
    }
}

extern "C" void kernel_launch(void* const* d_in, const int* in_sizes, int n_in,
                              void* d_out, int out_size, void* d_ws, size_t ws_size,
                              hipStream_t stream) {
    const float* x        = (const float*)d_in[0];
    const int*   rootidx  = (const int*)d_in[1];
    const int*   hist_tok = (const int*)d_in[2];
    const int*   seg      = (const int*)d_in[3];
    const float* emb      = (const float*)d_in[4];
    const float* w3       = (const float*)d_in[5];
    const float* cb3      = (const float*)d_in[6];
    const float* w4       = (const float*)d_in[7];
    const float* cb4      = (const float*)d_in[8];
    const float* w5       = (const float*)d_in[9];
    const float* cb5      = (const float*)d_in[10];
    const float* hist_w   = (const float*)d_in[11];
    const float* hist_b   = (const float*)d_in[12];
    const float* fw1      = (const float*)d_in[13];
    const float* fb1      = (const float*)d_in[14];
    const float* fw2      = (const float*)d_in[15];
    const float* fb2      = (const float*)d_in[16];
    float* out = (float*)d_out;

    // workspace layout (bytes)
    char* ws = (char*)d_ws;
    unsigned short* emb_bf  = (unsigned short*)(ws);                    // 30,000,000 B
    unsigned short* hist_bf = (unsigned short*)(ws + 30000000);         // 68,157,440 B
    unsigned short* W5f     = (unsigned short*)(ws + 98157440);         //  1,024,000 B
    float*          bias_all= (float*)(ws + 99181440);                  //      1,280 B
    unsigned short* w1b     = (unsigned short*)(ws + 99182720);         //    196,608 B

    emb_cvt<<<(50000 * DD / 4 + 255) / 256, 256, 0, stream>>>(emb, emb_bf, 50000 * DD / 4);
    emb_cvt<<<(HID2 * INFEAT / 4 + 255) / 256, 256, 0, stream>>>(fw1, w1b, HID2 * INFEAT / 4);
    prep_w<<<(10 * 5 * 20 * 512 + 255) / 256, 256, 0, stream>>>(w3, w4, w5, cb3, cb4, cb5, W5f, bias_all);
    gather_kernel<<<NB, 512, 0, stream>>>(hist_tok, seg, emb_bf, hist_bf);
    conv_kernel<<<NB / UPB, 768, 0, stream>>>(hist_bf, W5f, bias_all, hist_w, hist_b, out);
    fc_mfma<<<NB / FCM, 256, 0, stream>>>(x, rootidx, w1b, fb1, fw2, fb2, out);
}